// Round 13
// baseline (132.830 us; speedup 1.0000x reference)
//
#include <hip/hip_runtime.h>
#include <hip/hip_bf16.h>

#define B_ 2
#define T_ 2048
#define C_ 1024
#define H_ 16
#define D_ 64
#define M1 4096
#define N1 3072
#define K_ 1024

typedef __attribute__((ext_vector_type(8))) __bf16 bf16x8;
typedef __attribute__((ext_vector_type(4))) float f32x4;
typedef __attribute__((ext_vector_type(8))) unsigned short ushort8_t;
typedef __attribute__((ext_vector_type(4))) unsigned short ushort4_t;
typedef __attribute__((ext_vector_type(2))) unsigned int uint2_t;

static __device__ __forceinline__ unsigned short f2bf(float f) {
    unsigned int u = __builtin_bit_cast(unsigned int, f);
    u += 0x7fffu + ((u >> 16) & 1u);
    return (unsigned short)(u >> 16);
}
static __device__ __forceinline__ unsigned short f2bf_hw(float f) {
    return __builtin_bit_cast(unsigned short, (__bf16)f);
}
static __device__ __forceinline__ unsigned int packbf(float lo, float hi) {
    return (unsigned int)f2bf_hw(lo) | ((unsigned int)f2bf_hw(hi) << 16);
}
static __device__ __forceinline__ bf16x8 bload(const unsigned short* p) {
    return __builtin_bit_cast(bf16x8, *(const ushort8_t*)p);
}

// fast exp2 -> v_exp_f32
#if defined(__has_builtin)
#if __has_builtin(__builtin_amdgcn_exp2f)
#define HAVE_EXP2_BUILTIN 1
#endif
#endif
static __device__ __forceinline__ float fexp2(float x) {
#ifdef HAVE_EXP2_BUILTIN
    return __builtin_amdgcn_exp2f(x);
#else
    float r; asm("v_exp_f32 %0, %1" : "=v"(r) : "v"(x)); return r;
#endif
}

// ---- async global->LDS (16B per lane; LDS dest wave-uniform base + lane*16) ----
typedef __attribute__((address_space(1))) const unsigned int gu32;
typedef __attribute__((address_space(3))) unsigned int lu32;
static __device__ __forceinline__ void gld16(const void* g, void* l) {
    __builtin_amdgcn_global_load_lds((gu32*)g, (lu32*)l, 16, 0, 0);
}

#define VMCNT(n) asm volatile("s_waitcnt vmcnt(" #n ")" ::: "memory")
#define LGKM0    asm volatile("s_waitcnt lgkmcnt(0)" ::: "memory")

// ---------------- cast x -> bf16 ----------------
__global__ void cast_x_kernel(const float* __restrict__ in,
                              unsigned short* __restrict__ out, int n4) {
    int idx = blockIdx.x * blockDim.x + threadIdx.x;
    int stride = gridDim.x * blockDim.x;
    for (int i = idx; i < n4; i += stride) {
        float4 v = ((const float4*)in)[i];
        ushort4_t o;
        o.x = f2bf(v.x); o.y = f2bf(v.y); o.z = f2bf(v.z); o.w = f2bf(v.w);
        ((ushort4_t*)out)[i] = o;
    }
}

// ------------- transpose f32[K][N] -> bf16[N][K] -------------
__global__ void transpose_cast_kernel(const float* __restrict__ in,
                                      unsigned short* __restrict__ out,
                                      int K, int N) {
    __shared__ float tile[32][33];
    int tx = threadIdx.x & 31;
    int ty = threadIdx.x >> 5;
    int n0 = blockIdx.x * 32;
    int k0 = blockIdx.y * 32;
#pragma unroll
    for (int rr = 0; rr < 32; rr += 8)
        tile[ty + rr][tx] = in[(size_t)(k0 + ty + rr) * N + n0 + tx];
    __syncthreads();
#pragma unroll
    for (int rr = 0; rr < 32; rr += 8)
        out[(size_t)(n0 + ty + rr) * K + k0 + tx] = f2bf(tile[tx][ty + rr]);
}

// =================== GEMM common body (dbuf LDS via global_load_lds) ===================
// Granule XOR-swizzle: LDS slot s of row r holds global granule s ^ ((r>>1)&3);
// quad index (4r + slot) % 8 covers all 8 quads over any 8 fragment rows ->
// conflict-free ds_read_b128. Source pre-swizzled, dest linear (rule #21).

#define GEMM_PROLOGUE(BXE, BYE)                                                          \
    __shared__ unsigned short As[2][128 * 32];                                           \
    __shared__ unsigned short Bs[2][128 * 32];                                           \
    const int tid = threadIdx.x;                                                         \
    const int lane = tid & 63;                                                           \
    const int wave = tid >> 6;                                                           \
    const int g = lane >> 4, cl = lane & 15;                                             \
    const int wr = (wave >> 1) * 64, wc = (wave & 1) * 64;                               \
    const int row0 = (BXE) * 128;                                                        \
    const int col0 = (BYE) * 128;                                                        \
    const int srow = tid >> 2;  /* 0..63 */                                              \
    const int sgran = tid & 3;                                                           \
    f32x4 acc[4][4];                                                                     \
    _Pragma("unroll") for (int m = 0; m < 4; ++m)                                        \
        _Pragma("unroll") for (int n = 0; n < 4; ++n)                                    \
            acc[m][n] = (f32x4){0.f, 0.f, 0.f, 0.f};                                     \
    auto stage = [&](int buf, int k0) {                                                  \
        _Pragma("unroll") for (int c = 0; c < 2; ++c) {                                  \
            int r = srow + c * 64;                                                       \
            int lg = sgran ^ ((r >> 1) & 3);                                             \
            gld16(A + (size_t)(row0 + r) * K_ + k0 + lg * 8,                             \
                  (char*)&As[buf][0] + c * 4096 + wave * 1024);                          \
            gld16(Bt + (size_t)(col0 + r) * K_ + k0 + lg * 8,                            \
                  (char*)&Bs[buf][0] + c * 4096 + wave * 1024);                          \
        }                                                                                \
    };                                                                                   \
    stage(0, 0);                                                                         \
    int buf = 0;                                                                         \
    for (int k0 = 0; k0 < K_; k0 += 32) {                                                \
        if (k0 + 32 < K_) { stage(buf ^ 1, k0 + 32); VMCNT(4); }                         \
        else              { VMCNT(0); }                                                  \
        __builtin_amdgcn_s_barrier();                                                    \
        bf16x8 af[4], bfv[4];                                                            \
        _Pragma("unroll") for (int m = 0; m < 4; ++m) {                                  \
            int ra = wr + m * 16 + cl;                                                   \
            af[m] = bload(&As[buf][ra * 32 + (g ^ ((ra >> 1) & 3)) * 8]);                \
        }                                                                                \
        _Pragma("unroll") for (int n = 0; n < 4; ++n) {                                  \
            int rb = wc + n * 16 + cl;                                                   \
            bfv[n] = bload(&Bs[buf][rb * 32 + (g ^ ((rb >> 1) & 3)) * 8]);               \
        }                                                                                \
        _Pragma("unroll") for (int m = 0; m < 4; ++m)                                    \
            _Pragma("unroll") for (int n = 0; n < 4; ++n)                                \
                acc[m][n] = __builtin_amdgcn_mfma_f32_16x16x32_bf16(                     \
                    af[m], bfv[n], acc[m][n], 0, 0, 0);                                  \
        LGKM0;                                                                           \
        __builtin_amdgcn_s_barrier();                                                    \
        buf ^= 1;                                                                        \
    }

// ---------------- GEMM1: qkv = Xb @ Wt1^T + b ----------------
__global__ __launch_bounds__(256)
void gemm_qkv_kernel(const unsigned short* __restrict__ A,   // [4096][1024] bf16
                     const unsigned short* __restrict__ Bt,  // [3072][1024] bf16
                     const float* __restrict__ bias,         // [3072]
                     unsigned short* __restrict__ Qo,        // [BH][T][D] (pre-scaled)
                     unsigned short* __restrict__ Ko,        // [BH][T][D]
                     unsigned short* __restrict__ Vt)        // [BH][D][T]
{
    const int lin = blockIdx.x + gridDim.x * blockIdx.y;  // 0..767
    const int xcd = lin & 7;
    const int idx = lin >> 3;                              // 0..95
    const int bx = (xcd >> 1) * 8 + (idx & 7);             // 0..31
    const int by = (xcd & 1) * 12 + (idx >> 3);            // 0..23

    GEMM_PROLOGUE(bx, by)

    const float QSCALE = 0.125f * 1.44269504088896340736f;  // 1/sqrt(D) * log2(e)
#pragma unroll
    for (int m = 0; m < 4; ++m) {
        int i0 = row0 + wr + m * 16 + g * 4;
        int b = i0 >> 11, t0 = i0 & 2047;   // 4 consecutive t from t0 (same b)
#pragma unroll
        for (int n = 0; n < 4; ++n) {
            int j = col0 + wc + n * 16 + cl;
            int which = j >> 10;
            int c = j & 1023;
            int h = c >> 6, d = c & 63;
            float bv = bias[j];
            size_t bh = (size_t)(b * H_ + h);
            float v0 = acc[m][n][0] + bv;
            float v1 = acc[m][n][1] + bv;
            float v2 = acc[m][n][2] + bv;
            float v3 = acc[m][n][3] + bv;
            if (which == 2) {
                uint2_t w;
                w.x = packbf(v0, v1);
                w.y = packbf(v2, v3);
                *(uint2_t*)&Vt[(bh * D_ + d) * T_ + t0] = w;
            } else if (which == 0) {
                Qo[(bh * T_ + t0 + 0) * D_ + d] = f2bf_hw(v0 * QSCALE);
                Qo[(bh * T_ + t0 + 1) * D_ + d] = f2bf_hw(v1 * QSCALE);
                Qo[(bh * T_ + t0 + 2) * D_ + d] = f2bf_hw(v2 * QSCALE);
                Qo[(bh * T_ + t0 + 3) * D_ + d] = f2bf_hw(v3 * QSCALE);
            } else {
                Ko[(bh * T_ + t0 + 0) * D_ + d] = f2bf_hw(v0);
                Ko[(bh * T_ + t0 + 1) * D_ + d] = f2bf_hw(v1);
                Ko[(bh * T_ + t0 + 2) * D_ + d] = f2bf_hw(v2);
                Ko[(bh * T_ + t0 + 3) * D_ + d] = f2bf_hw(v3);
            }
        }
    }
}

// ---------------- GEMM2: out = AO @ Wt2^T + b (fp32 out) ----------------
__global__ __launch_bounds__(256)
void gemm_proj_kernel(const unsigned short* __restrict__ A,   // [4096][1024] bf16
                      const unsigned short* __restrict__ Bt,  // [1024][1024] bf16
                      const float* __restrict__ bias,         // [1024]
                      float* __restrict__ out)                // [4096][1024] f32
{
    GEMM_PROLOGUE(blockIdx.x, blockIdx.y)

#pragma unroll
    for (int m = 0; m < 4; ++m) {
        int i0 = row0 + wr + m * 16 + g * 4;
#pragma unroll
        for (int n = 0; n < 4; ++n) {
            int j = col0 + wc + n * 16 + cl;
            float bv = bias[j];
#pragma unroll
            for (int r = 0; r < 4; ++r)
                out[(size_t)(i0 + r) * C_ + j] = acc[m][n][r] + bv;
        }
    }
}

// ---------------- flash attention (causal, swapped QK^T, 32 q-rows/wave) ----------------
// Each wave owns TWO 16-row q-fragments (q0+w*16 and q0+64+w*16); block = 128
// q-rows. K/V LDS fragments are read ONCE and feed BOTH fragments' MFMAs ->
// LDS traffic per unit work halves (LDS pipe was the saturated resource).
// grid 512: xcd = lin&7; bh = xcd+8*(idx&3) (4 heads/XCD, L2-resident);
// qt = 15-(idx>>2) (long tiles first). LDS 48 KB -> 2 blocks/CU, 8 waves.
// Lane-local online softmax w/ defer-max THR=8; exp2 domain (Q pre-scaled).
__global__ __launch_bounds__(256, 2)
void attn_kernel(const unsigned short* __restrict__ Q,   // [BH][T][D], pre-scaled
                 const unsigned short* __restrict__ Kb,  // [BH][T][D]
                 const unsigned short* __restrict__ Vh_, // [BH][D][T]
                 unsigned short* __restrict__ AO)        // [B][T][C] bf16
{
    __shared__ unsigned short Klds[2][64 * 64];   // 16 KB
    __shared__ unsigned short Vlds[2][64 * 64];   // 16 KB
    __shared__ unsigned short Plds[4][32 * 64];   // 16 KB (32 P-rows per wave)
    const int lin = blockIdx.x;                   // 0..511
    const int idx = lin >> 3;                     // 0..63
    const int bh  = (lin & 7) + 8 * (idx & 3);    // 0..31, head pinned to one XCD
    const int qt  = 15 - (idx >> 2);              // 0..15, long tiles first
    const int b = bh >> 4, h = bh & 15;
    const int tid = threadIdx.x;
    const int lane = tid & 63;
    const int wave = tid >> 6;
    const int g = lane >> 4, cl = lane & 15;

    const unsigned short* Qh = Q + (size_t)bh * T_ * D_;
    const unsigned short* Kh = Kb + (size_t)bh * T_ * D_;
    const unsigned short* Vh = Vh_ + (size_t)bh * D_ * T_;

    const int srow = tid >> 3;  // 0..31
    const int sg   = tid & 7;
    const int pswz = (cl & 7) << 4;   // Plds byte-XOR (same involution write & read)

    auto stage = [&](int bufi, int kb) {
#pragma unroll
        for (int c = 0; c < 2; ++c) {
            int r = srow + c * 32;
            int lg = sg ^ (r & 7);
            gld16(Kh + (size_t)(kb + r) * D_ + lg * 8,
                  (char*)&Klds[bufi][0] + c * 4096 + wave * 1024);
            gld16(Vh + (size_t)r * T_ + kb + lg * 8,
                  (char*)&Vlds[bufi][0] + c * 4096 + wave * 1024);
        }
    };

    const int q0 = qt * 128 + wave * 16;
    int tq[2];
    tq[0] = q0 + cl;        // frag0 q row
    tq[1] = q0 + 64 + cl;   // frag1 q row

    bf16x8 qf[2][2];
#pragma unroll
    for (int hq = 0; hq < 2; ++hq)
#pragma unroll
        for (int c2 = 0; c2 < 2; ++c2)
            qf[hq][c2] = bload(Qh + (size_t)(q0 + hq * 64 + cl) * D_ + c2 * 32 + g * 8);

    f32x4 oacc[2][4];
#pragma unroll
    for (int hq = 0; hq < 2; ++hq)
#pragma unroll
        for (int n = 0; n < 4; ++n) oacc[hq][n] = (f32x4){0.f, 0.f, 0.f, 0.f};
    float m_run[2] = {-INFINITY, -INFINITY};
    float l_part[2] = {0.f, 0.f};

    const int nk = 2 * qt + 2;
    stage(0, 0);
    int buf = 0;
    for (int kt = 0; kt < nk; ++kt) {
        if (kt + 1 < nk) { stage(buf ^ 1, (kt + 1) * 64); VMCNT(4); }
        else             { VMCNT(0); }
        __builtin_amdgcn_s_barrier();

        const int kb = kt * 64;
        const bool do0 = (kt < nk - 1);   // frag0 fully past-causal on last tile
        // ---- QK^T (swapped): shared K fragments feed both q-frags ----
        f32x4 sc[2][4];
#pragma unroll
        for (int hq = 0; hq < 2; ++hq)
#pragma unroll
            for (int n = 0; n < 4; ++n) sc[hq][n] = (f32x4){0.f, 0.f, 0.f, 0.f};
        __builtin_amdgcn_s_setprio(1);
#pragma unroll
        for (int n = 0; n < 4; ++n) {
#pragma unroll
            for (int c2 = 0; c2 < 2; ++c2) {
                int pg = (c2 * 4 + g) ^ (cl & 7);
                bf16x8 kf = bload(&Klds[buf][(n * 16 + cl) * 64 + pg * 8]);
                if (do0)
                    sc[0][n] = __builtin_amdgcn_mfma_f32_16x16x32_bf16(kf, qf[0][c2], sc[0][n], 0, 0, 0);
                sc[1][n] = __builtin_amdgcn_mfma_f32_16x16x32_bf16(kf, qf[1][c2], sc[1][n], 0, 0, 0);
            }
        }
        __builtin_amdgcn_s_setprio(0);
        // ---- causal masks: frag0 at kt==nk-2, frag1 at kt==nk-1 ----
        if (kt == nk - 2) {
#pragma unroll
            for (int n = 0; n < 4; ++n) {
                int k4 = kb + n * 16 + g * 4;
#pragma unroll
                for (int r = 0; r < 4; ++r)
                    if (k4 + r > tq[0]) sc[0][n][r] = -INFINITY;
            }
        }
        if (kt == nk - 1) {
#pragma unroll
            for (int n = 0; n < 4; ++n) {
                int k4 = kb + n * 16 + g * 4;
#pragma unroll
                for (int r = 0; r < 4; ++r)
                    if (k4 + r > tq[1]) sc[1][n][r] = -INFINITY;
            }
        }
        // ---- lane-local online softmax per frag (defer-max THR=8) ----
        float p[2][4][4];
#pragma unroll
        for (int hq = 0; hq < 2; ++hq) {
            if (hq == 0 && !do0) continue;
            float mx[4];
#pragma unroll
            for (int n = 0; n < 4; ++n)
                mx[n] = fmaxf(fmaxf(sc[hq][n][0], sc[hq][n][1]),
                              fmaxf(sc[hq][n][2], sc[hq][n][3]));
            float lm = fmaxf(fmaxf(mx[0], mx[1]), fmaxf(mx[2], mx[3]));
            if (!__all(lm <= m_run[hq] + 8.f)) {
                float vmax = lm;
                vmax = fmaxf(vmax, __shfl_xor(vmax, 16, 64));
                vmax = fmaxf(vmax, __shfl_xor(vmax, 32, 64));
                float mn = fmaxf(m_run[hq], vmax);
                float alpha = fexp2(m_run[hq] - mn);
                l_part[hq] *= alpha;
#pragma unroll
                for (int n = 0; n < 4; ++n)
#pragma unroll
                    for (int r = 0; r < 4; ++r) oacc[hq][n][r] *= alpha;
                m_run[hq] = mn;
            }
            float psub[4];
#pragma unroll
            for (int n = 0; n < 4; ++n) {
#pragma unroll
                for (int r = 0; r < 4; ++r) p[hq][n][r] = fexp2(sc[hq][n][r] - m_run[hq]);
                psub[n] = (p[hq][n][0] + p[hq][n][1]) + (p[hq][n][2] + p[hq][n][3]);
            }
            l_part[hq] += (psub[0] + psub[1]) + (psub[2] + psub[3]);
            // P-write: 4x ds_write_b64 into own (swizzled) q-row
#pragma unroll
            for (int n = 0; n < 4; ++n) {
                uint2_t w;
                w.x = packbf(p[hq][n][0], p[hq][n][1]);
                w.y = packbf(p[hq][n][2], p[hq][n][3]);
                *(uint2_t*)((char*)&Plds[wave][0] +
                    (((hq * 16 + cl) * 128 + n * 32 + g * 8) ^ pswz)) = w;
            }
        }
        // ---- P fragments ----
        bf16x8 pf[2][2];
#pragma unroll
        for (int hq = 0; hq < 2; ++hq) {
            if (hq == 0 && !do0) continue;
#pragma unroll
            for (int kk = 0; kk < 2; ++kk)
                pf[hq][kk] = bload((const unsigned short*)((char*)&Plds[wave][0] +
                    (((hq * 16 + cl) * 128 + kk * 64 + g * 16) ^ pswz)));
        }
        // ---- PV (swapped): shared V fragments feed both q-frags ----
        __builtin_amdgcn_s_setprio(1);
#pragma unroll
        for (int n = 0; n < 4; ++n) {
#pragma unroll
            for (int kk = 0; kk < 2; ++kk) {
                int pg = (kk * 4 + g) ^ (cl & 7);
                bf16x8 vfr = bload(&Vlds[buf][(n * 16 + cl) * 64 + pg * 8]);
                if (do0)
                    oacc[0][n] = __builtin_amdgcn_mfma_f32_16x16x32_bf16(vfr, pf[0][kk], oacc[0][n], 0, 0, 0);
                oacc[1][n] = __builtin_amdgcn_mfma_f32_16x16x32_bf16(vfr, pf[1][kk], oacc[1][n], 0, 0, 0);
            }
        }
        __builtin_amdgcn_s_setprio(0);
        LGKM0;
        __builtin_amdgcn_s_barrier();
        buf ^= 1;
    }
    // ---- epilogue: per frag, reduce l across g-lanes, then packed store ----
#pragma unroll
    for (int hq = 0; hq < 2; ++hq) {
        float lt = l_part[hq];
        lt += __shfl_xor(lt, 16, 64);
        lt += __shfl_xor(lt, 32, 64);
        float inv = 1.f / lt;
#pragma unroll
        for (int n = 0; n < 4; ++n) {
            uint2_t w;
            w.x = packbf(oacc[hq][n][0] * inv, oacc[hq][n][1] * inv);
            w.y = packbf(oacc[hq][n][2] * inv, oacc[hq][n][3] * inv);
            *(uint2_t*)&AO[((size_t)b * T_ + tq[hq]) * C_ + h * D_ + n * 16 + g * 4] = w;
        }
    }
}

extern "C" void kernel_launch(void* const* d_in, const int* in_sizes, int n_in,
                              void* d_out, int out_size, void* d_ws, size_t ws_size,
                              hipStream_t stream) {
    (void)in_sizes; (void)n_in; (void)out_size; (void)ws_size;
    const float* x      = (const float*)d_in[0];
    const float* w_attn = (const float*)d_in[1];
    const float* b_attn = (const float*)d_in[2];
    const float* w_proj = (const float*)d_in[3];
    const float* b_proj = (const float*)d_in[4];
    float* out = (float*)d_out;

    char* ws = (char*)d_ws;
    unsigned short* Xb  = (unsigned short*)(ws);
    unsigned short* Wt1 = (unsigned short*)(ws + ((size_t)8  << 20));
    unsigned short* Wt2 = (unsigned short*)(ws + ((size_t)14 << 20));
    unsigned short* Qb  = (unsigned short*)(ws + ((size_t)16 << 20));
    unsigned short* Kb  = (unsigned short*)(ws + ((size_t)24 << 20));
    unsigned short* Vt  = (unsigned short*)(ws + ((size_t)32 << 20));
    unsigned short* AO  = Xb;  // Xb dead after gemm_qkv

    cast_x_kernel<<<1024, 256, 0, stream>>>(x, Xb, (M1 * K_) / 4);
    transpose_cast_kernel<<<dim3(N1 / 32, K_ / 32), 256, 0, stream>>>(w_attn, Wt1, K_, N1);
    transpose_cast_kernel<<<dim3(C_ / 32, K_ / 32), 256, 0, stream>>>(w_proj, Wt2, K_, C_);
    gemm_qkv_kernel<<<dim3(M1 / 128, N1 / 128), 256, 0, stream>>>(Xb, Wt1, b_attn, Qb, Kb, Vt);
    attn_kernel<<<512, 256, 0, stream>>>(Qb, Kb, Vt, AO);
    gemm_proj_kernel<<<dim3(M1 / 128, C_ / 128), 256, 0, stream>>>(AO, Wt2, b_proj, out);
}